// Round 17
// baseline (3041.306 us; speedup 1.0000x reference)
//
#include <hip/hip_runtime.h>

typedef unsigned short u16;
typedef unsigned int u32;
typedef unsigned long long u64;
typedef short v8s __attribute__((ext_vector_type(8)));
typedef float v4f __attribute__((ext_vector_type(4)));
typedef unsigned int u32x4 __attribute__((ext_vector_type(4)));

// T=256, B=64, NIN=H=512, NOUT=512, 4H=2048, T*B=16384
#define TT 256
#define BB 64
#define HH 512
#define G4 2048
#define MTB 16384

static __device__ __forceinline__ float bf2f(u16 u) {
    u32 x = ((u32)u) << 16;
    union { u32 i; float f; } c; c.i = x; return c.f;
}
static __device__ __forceinline__ u16 f2bf(float f) {
    union { float f; u32 i; } c; c.f = f;
    u32 u = c.i;
    u += 0x7fffu + ((u >> 16) & 1u);   // RNE
    return (u16)(u >> 16);
}

__global__ __launch_bounds__(256) void cvt_bf16(const float* __restrict__ src,
                                                u16* __restrict__ dst, int n) {
    int i = blockIdx.x * blockDim.x + threadIdx.x;
    int stride = gridDim.x * blockDim.x;
    for (int j = i * 4; j < n; j += stride * 4) {
        float4 v = *reinterpret_cast<const float4*>(src + j);
        ushort4 o;
        o.x = f2bf(v.x); o.y = f2bf(v.y); o.z = f2bf(v.z); o.w = f2bf(v.w);
        *reinterpret_cast<ushort4*>(dst + j) = o;
    }
}

// C[M][N] = A[M][K] * B[N][K]^T (+ bias).  A,B bf16 K-contiguous; 128x128 tile, BK=64,
// 4 waves in 2x2, each wave 64x64 = 4x4 16x16x32 fragments. M,N,K multiples of 128 assumed.
template<bool OUT_BF16, bool BIAS_M>
__global__ __launch_bounds__(256) void gemm_bt(const u16* __restrict__ A,
                                               const u16* __restrict__ Bm,
                                               void* __restrict__ Cv,
                                               const float* __restrict__ bias1,
                                               const float* __restrict__ bias2,
                                               int M, int N, int K) {
    __shared__ u16 lds_a[128 * 64];
    __shared__ u16 lds_b[128 * 64];
    const int tid = threadIdx.x, lane = tid & 63;
    const int m0 = blockIdx.y * 128, n0 = blockIdx.x * 128;
    const int wid = tid >> 6, wm = wid >> 1, wn = wid & 1;
    v4f acc[4][4] = {};

    const int srow  = tid >> 3;
    const int skoff = (tid & 7) * 8;
    const u16* Ag = A + (size_t)(m0 + srow) * K + skoff;
    const u16* Bg = Bm + (size_t)(n0 + srow) * K + skoff;
    u16* la = lds_a + srow * 64 + skoff;
    u16* lb = lds_b + srow * 64 + skoff;

    for (int k0 = 0; k0 < K; k0 += 64) {
        #pragma unroll
        for (int q = 0; q < 4; ++q) {
            *reinterpret_cast<v8s*>(la + q * 32 * 64) =
                *reinterpret_cast<const v8s*>(Ag + (size_t)q * 32 * K + k0);
            *reinterpret_cast<v8s*>(lb + q * 32 * 64) =
                *reinterpret_cast<const v8s*>(Bg + (size_t)q * 32 * K + k0);
        }
        __syncthreads();
        #pragma unroll
        for (int kk = 0; kk < 2; ++kk) {
            v8s af[4], bfr[4];
            #pragma unroll
            for (int i = 0; i < 4; ++i)
                af[i] = *reinterpret_cast<const v8s*>(
                    lds_a + (wm * 64 + i * 16 + (lane & 15)) * 64 + kk * 32 + (lane >> 4) * 8);
            #pragma unroll
            for (int i = 0; i < 4; ++i)
                bfr[i] = *reinterpret_cast<const v8s*>(
                    lds_b + (wn * 64 + i * 16 + (lane & 15)) * 64 + kk * 32 + (lane >> 4) * 8);
            #pragma unroll
            for (int i = 0; i < 4; ++i)
                #pragma unroll
                for (int j = 0; j < 4; ++j)
                    acc[i][j] = __builtin_amdgcn_mfma_f32_16x16x32_bf16(af[i], bfr[j], acc[i][j], 0, 0, 0);
        }
        __syncthreads();
    }
    #pragma unroll
    for (int i = 0; i < 4; ++i) {
        #pragma unroll
        for (int j = 0; j < 4; ++j) {
            #pragma unroll
            for (int r = 0; r < 4; ++r) {
                int m = m0 + wm * 64 + i * 16 + (lane >> 4) * 4 + r;
                int n = n0 + wn * 64 + j * 16 + (lane & 15);
                float v = acc[i][j][r];
                if (BIAS_M) { v += bias1[m]; if (bias2) v += bias2[m]; }
                else        { v += bias1[n]; }
                if (OUT_BF16) ((u16*)Cv)[(size_t)m * N + n] = f2bf(v);
                else          ((float*)Cv)[(size_t)m * N + n] = v;
            }
        }
    }
}

static __device__ __forceinline__ float sigm(float x) { return 1.f / (1.f + __expf(-x)); }
static __device__ __forceinline__ float tanh_(float x) { return 2.f / (1.f + __expf(-2.f * x)) - 1.f; }

static __device__ __forceinline__ u64 ald(const u64* p) {
    return __hip_atomic_load(p, __ATOMIC_RELAXED, __HIP_MEMORY_SCOPE_AGENT);
}
// validate fragment: all 8 tagged words carry tag tg (high 16) -> pack payload bf16x8
static __device__ __forceinline__ bool vfrag(u32x4 a, u32x4 b, u32 tg, v8s* out) {
    u32 bad = ((a.x ^ tg) | (a.y ^ tg) | (a.z ^ tg) | (a.w ^ tg)
             | (b.x ^ tg) | (b.y ^ tg) | (b.z ^ tg) | (b.w ^ tg)) & 0xFFFF0000u;
    union { u32 w[4]; v8s v; } P;
    P.w[0] = (a.x & 0xFFFFu) | (a.y << 16);
    P.w[1] = (a.z & 0xFFFFu) | (a.w << 16);
    P.w[2] = (b.x & 0xFFFFu) | (b.y << 16);
    P.w[3] = (b.z & 0xFFFFu) | (b.w << 16);
    *out = P.v;
    return __all(bad == 0);
}

// Persistent bidirectional LSTM recurrence — tagged ring + INLINE-ASM batched loads.
// Established: flag sync = 4-5 serial IC legs ~5.25us/step (invariant R3-R16);
// tagged detect+data fusion is the only 2-leg transport, numerically proven
// (R7/R14), but C-level batching was re-split by the compiler (R15: VGPR=108).
// Here the 32 sc0 dwordx4 loads are pinned in two inline-asm blocks; ONE
// s_waitcnt vmcnt(0) + sched_barrier(0) fence (rule-18 pattern) orders all
// validation after the wait. Retries reload ONLY missing fragments via coherent
// u64 atomic loads with s_sleep(1) backoff. Producer: gates -> 2 tagged u64 ring
// stores + 1 plain h_all store, fire-and-forget (no drain, no flag).
// Ring: [4][64][1024] tagged u32, depth-4 safety: wave at step t validated all of
// t-1 => every wave finished writing t-1 => finished reading t-2 => nobody still
// reads the t-4 data this store overwrites. 0xFF-memset per call (stale tags never
// match). 64 blocks x 256 thr: bx>>5=dir, &31=cg; wave nf owns b=nf*16..+15,
// all 4 gates, K=512; w_hh slice (64KB) LDS-resident.
__global__ __launch_bounds__(256, 1) void lstm_persist(
    const u16* __restrict__ w_hh,        // [2][2048][512]
    const u16* __restrict__ xgT,         // [2][2048][16384]  col = t*64+b
    u16* __restrict__ h_all,             // [256*64][1024] untagged (FC input)
    u32* __restrict__ ring)              // [4][64][1024] tagged (t<<16 | bf16)
{
    __shared__ u16 wlds[4 * 16 * 64 * 8];    // [G][kk][lane][8 bf16] = 64 KB
    const int bx = blockIdx.x;
    const int d = bx >> 5, cg = bx & 31;
    const int lane = threadIdx.x & 63, nf = threadIdx.x >> 6;
    const int lrow = lane & 15, lk = lane >> 4;
    const int b = nf * 16 + lrow;        // this lane's batch column

    // ---- stage A fragments into LDS (once): wave nf fills gate G = nf ----
    {
        const int G = nf;
        const u16* wrow = w_hh + ((size_t)d * G4 + G * HH + cg * 16 + lrow) * HH + lk * 8;
        #pragma unroll
        for (int kk = 0; kk < 16; ++kk)
            *reinterpret_cast<v8s*>(&wlds[((G * 16 + kk) * 64 + lane) * 8]) =
                *reinterpret_cast<const v8s*>(wrow + kk * 32);
    }
    __syncthreads();

    float c[4] = {0.f, 0.f, 0.f, 0.f};

    for (int s = 0; s < TT; ++s) {
        const int t = d ? (TT - 1 - s) : s;

        // ---- issue THIS step's xg loads (retire under the batched wait) ----
        u16 xgr[16];
        {
            const u16* xgb = xgT + (size_t)d * G4 * MTB + (size_t)t * BB + b;
            #pragma unroll
            for (int G = 0; G < 4; ++G)
                #pragma unroll
                for (int r = 0; r < 4; ++r)
                    xgr[G * 4 + r] = xgb[(size_t)(G * HH + cg * 16 + lk * 4 + r) * MTB];
        }

        v4f acc[4] = {};
        if (s > 0) {
            const int tprev = d ? (t + 1) : (t - 1);
            const u32 tg = (u32)tprev << 16;
            const u32* rp = ring + ((size_t)(tprev & 3) * BB + b) * 1024 + d * HH + lk * 8;
            u32x4 ra[16], rb[16];
            // ---- pass 1: 32 coherent dwordx4 loads pinned in asm, ONE wait ----
            asm volatile(
                "global_load_dwordx4 %0, %16, off sc0\n\t"
                "global_load_dwordx4 %1, %16, off offset:16 sc0\n\t"
                "global_load_dwordx4 %2, %16, off offset:128 sc0\n\t"
                "global_load_dwordx4 %3, %16, off offset:144 sc0\n\t"
                "global_load_dwordx4 %4, %16, off offset:256 sc0\n\t"
                "global_load_dwordx4 %5, %16, off offset:272 sc0\n\t"
                "global_load_dwordx4 %6, %16, off offset:384 sc0\n\t"
                "global_load_dwordx4 %7, %16, off offset:400 sc0\n\t"
                "global_load_dwordx4 %8, %16, off offset:512 sc0\n\t"
                "global_load_dwordx4 %9, %16, off offset:528 sc0\n\t"
                "global_load_dwordx4 %10, %16, off offset:640 sc0\n\t"
                "global_load_dwordx4 %11, %16, off offset:656 sc0\n\t"
                "global_load_dwordx4 %12, %16, off offset:768 sc0\n\t"
                "global_load_dwordx4 %13, %16, off offset:784 sc0\n\t"
                "global_load_dwordx4 %14, %16, off offset:896 sc0\n\t"
                "global_load_dwordx4 %15, %16, off offset:912 sc0"
                : "=&v"(ra[0]), "=&v"(rb[0]), "=&v"(ra[1]), "=&v"(rb[1]),
                  "=&v"(ra[2]), "=&v"(rb[2]), "=&v"(ra[3]), "=&v"(rb[3]),
                  "=&v"(ra[4]), "=&v"(rb[4]), "=&v"(ra[5]), "=&v"(rb[5]),
                  "=&v"(ra[6]), "=&v"(rb[6]), "=&v"(ra[7]), "=&v"(rb[7])
                : "v"(rp) : "memory");
            asm volatile(
                "global_load_dwordx4 %0, %16, off offset:1024 sc0\n\t"
                "global_load_dwordx4 %1, %16, off offset:1040 sc0\n\t"
                "global_load_dwordx4 %2, %16, off offset:1152 sc0\n\t"
                "global_load_dwordx4 %3, %16, off offset:1168 sc0\n\t"
                "global_load_dwordx4 %4, %16, off offset:1280 sc0\n\t"
                "global_load_dwordx4 %5, %16, off offset:1296 sc0\n\t"
                "global_load_dwordx4 %6, %16, off offset:1408 sc0\n\t"
                "global_load_dwordx4 %7, %16, off offset:1424 sc0\n\t"
                "global_load_dwordx4 %8, %16, off offset:1536 sc0\n\t"
                "global_load_dwordx4 %9, %16, off offset:1552 sc0\n\t"
                "global_load_dwordx4 %10, %16, off offset:1664 sc0\n\t"
                "global_load_dwordx4 %11, %16, off offset:1680 sc0\n\t"
                "global_load_dwordx4 %12, %16, off offset:1792 sc0\n\t"
                "global_load_dwordx4 %13, %16, off offset:1808 sc0\n\t"
                "global_load_dwordx4 %14, %16, off offset:1920 sc0\n\t"
                "global_load_dwordx4 %15, %16, off offset:1936 sc0"
                : "=&v"(ra[8]),  "=&v"(rb[8]),  "=&v"(ra[9]),  "=&v"(rb[9]),
                  "=&v"(ra[10]), "=&v"(rb[10]), "=&v"(ra[11]), "=&v"(rb[11]),
                  "=&v"(ra[12]), "=&v"(rb[12]), "=&v"(ra[13]), "=&v"(rb[13]),
                  "=&v"(ra[14]), "=&v"(rb[14]), "=&v"(ra[15]), "=&v"(rb[15])
                : "v"(rp) : "memory");
            asm volatile("s_waitcnt vmcnt(0)" ::: "memory");
            __builtin_amdgcn_sched_barrier(0);   // rule-18 fence: no hoist past wait
            // ---- validate + MFMA valid fragments ----
            u32 valid = 0;
            #pragma unroll
            for (int kk = 0; kk < 16; ++kk) {
                v8s bfv;
                if (vfrag(ra[kk], rb[kk], tg, &bfv)) {
                    #pragma unroll
                    for (int G = 0; G < 4; ++G) {
                        v8s af = *reinterpret_cast<const v8s*>(
                            &wlds[((G * 16 + kk) * 64 + lane) * 8]);
                        acc[G] = __builtin_amdgcn_mfma_f32_16x16x32_bf16(af, bfv, acc[G], 0, 0, 0);
                    }
                    valid |= 1u << kk;
                }
            }
            // ---- retry rounds: reload ONLY missing fragments (coherent u64) ----
            while (valid != 0xFFFFu) {
                __builtin_amdgcn_s_sleep(1);
                #pragma unroll
                for (int kk = 0; kk < 16; ++kk)
                    if (!(valid & (1u << kk))) {
                        const u64* p = (const u64*)(rp + kk * 32);
                        u64 q0 = ald(p), q1 = ald(p + 1), q2 = ald(p + 2), q3 = ald(p + 3);
                        ra[kk] = (u32x4){(u32)q0, (u32)(q0 >> 32), (u32)q1, (u32)(q1 >> 32)};
                        rb[kk] = (u32x4){(u32)q2, (u32)(q2 >> 32), (u32)q3, (u32)(q3 >> 32)};
                        v8s bfv;
                        if (vfrag(ra[kk], rb[kk], tg, &bfv)) {
                            #pragma unroll
                            for (int G = 0; G < 4; ++G) {
                                v8s af = *reinterpret_cast<const v8s*>(
                                    &wlds[((G * 16 + kk) * 64 + lane) * 8]);
                                acc[G] = __builtin_amdgcn_mfma_f32_16x16x32_bf16(af, bfv, acc[G], 0, 0, 0);
                            }
                            valid |= 1u << kk;
                        }
                    }
            }
        }
        // ---- gates + state update (all in this lane) ----
        const u32 tgo = (u32)t << 16;
        u32 hw[4];
        ushort4 hout;
        #pragma unroll
        for (int r = 0; r < 4; ++r) {
            float pi = acc[0][r] + bf2f(xgr[0 * 4 + r]);
            float pf = acc[1][r] + bf2f(xgr[1 * 4 + r]);
            float pg = acc[2][r] + bf2f(xgr[2 * 4 + r]);
            float po = acc[3][r] + bf2f(xgr[3 * 4 + r]);
            float iv = sigm(pi), fv = sigm(pf), gv = tanh_(pg), ov = sigm(po);
            float cc = fv * c[r] + iv * gv;
            c[r] = cc;
            u16 hv = f2bf(ov * tanh_(cc));
            hw[r] = tgo | (u32)hv;
            ((u16*)&hout)[r] = hv;
        }
        // ---- fire-and-forget: tagged ring (sync) + plain h_all (FC) ----
        const int j0 = cg * 16 + lk * 4;
        u64* rq = (u64*)(ring + ((size_t)(t & 3) * BB + b) * 1024 + d * HH + j0);
        __hip_atomic_store(rq,     (u64)hw[0] | ((u64)hw[1] << 32),
                           __ATOMIC_RELAXED, __HIP_MEMORY_SCOPE_AGENT);
        __hip_atomic_store(rq + 1, (u64)hw[2] | ((u64)hw[3] << 32),
                           __ATOMIC_RELAXED, __HIP_MEMORY_SCOPE_AGENT);
        union { ushort4 v; u64 q; } hu; hu.v = hout;
        *reinterpret_cast<u64*>(h_all + ((size_t)t * BB + b) * 1024 + d * HH + j0) = hu.q;
    }
}

extern "C" void kernel_launch(void* const* d_in, const int* in_sizes, int n_in,
                              void* d_out, int out_size, void* d_ws, size_t ws_size,
                              hipStream_t stream) {
    const float* x    = (const float*)d_in[0];
    const float* wihf = (const float*)d_in[1];
    const float* whhf = (const float*)d_in[2];
    const float* bihf = (const float*)d_in[3];
    const float* bhhf = (const float*)d_in[4];
    const float* wihb = (const float*)d_in[5];
    const float* whhb = (const float*)d_in[6];
    const float* bihb = (const float*)d_in[7];
    const float* bhhb = (const float*)d_in[8];
    const float* fcw  = (const float*)d_in[9];
    const float* fcb  = (const float*)d_in[10];

    char* ws = (char*)d_ws;
    size_t off = 0;
    auto alloc = [&](size_t bytes) {
        off = (off + 255) & ~(size_t)255;
        char* p = ws + off; off += bytes; return p;
    };
    u16* x_bf    = (u16*)alloc((size_t)MTB * 512 * 2);        // 16.8 MB
    u16* wih_bf  = (u16*)alloc((size_t)2 * G4 * 512 * 2);     // 4.2 MB
    u16* whh_bf  = (u16*)alloc((size_t)2 * G4 * 512 * 2);     // 4.2 MB
    u16* fcw_bf  = (u16*)alloc((size_t)512 * 1024 * 2);       // 1.0 MB
    u16* xgT     = (u16*)alloc((size_t)2 * G4 * MTB * 2);     // 134.2 MB
    u16* h_all   = (u16*)alloc((size_t)MTB * 1024 * 2);       // 33.6 MB
    u32* ring    = (u32*)alloc((size_t)4 * BB * 1024 * 4);    // 1.0 MB tagged ring
    (void)ws_size;

    // ---- convert inputs to bf16 ----
    cvt_bf16<<<1024, 256, 0, stream>>>(x, x_bf, MTB * 512);
    cvt_bf16<<<256, 256, 0, stream>>>(wihf, wih_bf, G4 * 512);
    cvt_bf16<<<256, 256, 0, stream>>>(wihb, wih_bf + (size_t)G4 * 512, G4 * 512);
    cvt_bf16<<<256, 256, 0, stream>>>(whhf, whh_bf, G4 * 512);
    cvt_bf16<<<256, 256, 0, stream>>>(whhb, whh_bf + (size_t)G4 * 512, G4 * 512);
    cvt_bf16<<<128, 256, 0, stream>>>(fcw, fcw_bf, 512 * 1024);

    // ---- clear stale ring tags (every call: graph replays reuse the buffer) ----
    hipMemsetAsync(ring, 0xFF, (size_t)4 * BB * 1024 * 4, stream);

    // ---- phase 1: xgT[d] = w_ih[d] @ x^T + (b_ih + b_hh), bf16 out, gate-major ----
    gemm_bt<true, true><<<dim3(MTB / 128, G4 / 128), 256, 0, stream>>>(
        wih_bf, x_bf, xgT, bihf, bhhf, G4, MTB, 512);
    gemm_bt<true, true><<<dim3(MTB / 128, G4 / 128), 256, 0, stream>>>(
        wih_bf + (size_t)G4 * 512, x_bf, xgT + (size_t)G4 * MTB, bihb, bhhb, G4, MTB, 512);

    // ---- phase 2: persistent recurrence, tagged ring + asm batched loads ----
    lstm_persist<<<64, 256, 0, stream>>>(whh_bf, xgT, h_all, ring);

    // ---- phase 3: out = h_all @ fc_w^T + fc_b, fp32 out ----
    gemm_bt<false, false><<<dim3(512 / 128, MTB / 128), 256, 0, stream>>>(
        h_all, fcw_bf, d_out, fcb, nullptr, MTB, 512, 1024);
}

// Round 18
// 1589.957 us; speedup vs baseline: 1.9128x; 1.9128x over previous
//
#include <hip/hip_runtime.h>

typedef unsigned short u16;
typedef unsigned int u32;
typedef unsigned long long u64;
typedef short v8s __attribute__((ext_vector_type(8)));
typedef float v4f __attribute__((ext_vector_type(4)));

// T=256, B=64, NIN=H=512, NOUT=512, 4H=2048, T*B=16384
#define TT 256
#define BB 64
#define HH 512
#define G4 2048
#define MTB 16384

static __device__ __forceinline__ float bf2f(u16 u) {
    u32 x = ((u32)u) << 16;
    union { u32 i; float f; } c; c.i = x; return c.f;
}
static __device__ __forceinline__ u16 f2bf(float f) {
    union { float f; u32 i; } c; c.f = f;
    u32 u = c.i;
    u += 0x7fffu + ((u >> 16) & 1u);   // RNE
    return (u16)(u >> 16);
}

__global__ __launch_bounds__(256) void cvt_bf16(const float* __restrict__ src,
                                                u16* __restrict__ dst, int n) {
    int i = blockIdx.x * blockDim.x + threadIdx.x;
    int stride = gridDim.x * blockDim.x;
    for (int j = i * 4; j < n; j += stride * 4) {
        float4 v = *reinterpret_cast<const float4*>(src + j);
        ushort4 o;
        o.x = f2bf(v.x); o.y = f2bf(v.y); o.z = f2bf(v.z); o.w = f2bf(v.w);
        *reinterpret_cast<ushort4*>(dst + j) = o;
    }
}

// C[M][N] = A[M][K] * B[N][K]^T (+ bias).  A,B bf16 K-contiguous; 128x128 tile, BK=64,
// 4 waves in 2x2, each wave 64x64 = 4x4 16x16x32 fragments. M,N,K multiples of 128.
// Staging upgraded to global_load_lds width-16 (m93->m97 ladder step, +69% measured):
// per k-step each wave issues 4 A + 4 B gload_lds (1KB each: 64 lanes x 16B), LDS dest
// linear row-major [row][64] (dest = uniform base + lane*16; lane l -> row q*8+(l>>3),
// col (l&7)*8 — matches per-lane global src), ONE vmcnt(0) + barrier, compute unchanged.
// Both sides linear (rule 21: no swizzle with gload_lds).
template<bool OUT_BF16, bool BIAS_M>
__global__ __launch_bounds__(256) void gemm_bt(const u16* __restrict__ A,
                                               const u16* __restrict__ Bm,
                                               void* __restrict__ Cv,
                                               const float* __restrict__ bias1,
                                               const float* __restrict__ bias2,
                                               int M, int N, int K) {
    __shared__ u16 lds_a[128 * 64];
    __shared__ u16 lds_b[128 * 64];
    const int tid = threadIdx.x, lane = tid & 63;
    const int m0 = blockIdx.y * 128, n0 = blockIdx.x * 128;
    const int wid = tid >> 6, wm = wid >> 1, wn = wid & 1;
    v4f acc[4][4] = {};

    const int lrow8 = lane >> 3;         // 0..7 row within 8-row stripe
    const int lcol8 = (lane & 7) * 8;    // bf16 col offset within 64-wide k

    for (int k0 = 0; k0 < K; k0 += 64) {
        #pragma unroll
        for (int i = 0; i < 4; ++i) {
            const int q = wid * 4 + i;   // 16 stripes of 8 rows
            const u16* ga = A  + (size_t)(m0 + q * 8 + lrow8) * K + k0 + lcol8;
            const u16* gb = Bm + (size_t)(n0 + q * 8 + lrow8) * K + k0 + lcol8;
            __builtin_amdgcn_global_load_lds(
                (const __attribute__((address_space(1))) void*)ga,
                (__attribute__((address_space(3))) void*)(lds_a + q * 512), 16, 0, 0);
            __builtin_amdgcn_global_load_lds(
                (const __attribute__((address_space(1))) void*)gb,
                (__attribute__((address_space(3))) void*)(lds_b + q * 512), 16, 0, 0);
        }
        asm volatile("s_waitcnt vmcnt(0)" ::: "memory");
        __syncthreads();
        #pragma unroll
        for (int kk = 0; kk < 2; ++kk) {
            v8s af[4], bfr[4];
            #pragma unroll
            for (int i = 0; i < 4; ++i)
                af[i] = *reinterpret_cast<const v8s*>(
                    lds_a + (wm * 64 + i * 16 + (lane & 15)) * 64 + kk * 32 + (lane >> 4) * 8);
            #pragma unroll
            for (int i = 0; i < 4; ++i)
                bfr[i] = *reinterpret_cast<const v8s*>(
                    lds_b + (wn * 64 + i * 16 + (lane & 15)) * 64 + kk * 32 + (lane >> 4) * 8);
            #pragma unroll
            for (int i = 0; i < 4; ++i)
                #pragma unroll
                for (int j = 0; j < 4; ++j)
                    acc[i][j] = __builtin_amdgcn_mfma_f32_16x16x32_bf16(af[i], bfr[j], acc[i][j], 0, 0, 0);
        }
        __syncthreads();
    }
    // epilogue: D col = lane&15 (n), row = (lane>>4)*4 + reg (m)
    #pragma unroll
    for (int i = 0; i < 4; ++i) {
        #pragma unroll
        for (int j = 0; j < 4; ++j) {
            #pragma unroll
            for (int r = 0; r < 4; ++r) {
                int m = m0 + wm * 64 + i * 16 + (lane >> 4) * 4 + r;
                int n = n0 + wn * 64 + j * 16 + (lane & 15);
                float v = acc[i][j][r];
                if (BIAS_M) { v += bias1[m]; if (bias2) v += bias2[m]; }
                else        { v += bias1[n]; }
                if (OUT_BF16) ((u16*)Cv)[(size_t)m * N + n] = f2bf(v);
                else          ((float*)Cv)[(size_t)m * N + n] = v;
            }
        }
    }
}

static __device__ __forceinline__ float sigm(float x) { return 1.f / (1.f + __expf(-x)); }
static __device__ __forceinline__ float tanh_(float x) { return 2.f / (1.f + __expf(-2.f * x)) - 1.f; }

// Persistent bidirectional LSTM recurrence — R11 verbatim (best measured: 1498 total).
// Established floor: ~5.25us/step = flag sync legs (drain, publish, detect, h-load),
// invariant to traffic (R11), publish mechanism (R9/R11), packing (R12), phase
// interleave (R16), XCD-local (R13 hang), tagged transport (R7/R14/R15/R17).
// One aggregated counter per (d,nf) group; producers lane0 fetch_add; consumers
// all-lane same-address load (merged transaction). w_hh slice (64KB) LDS-resident;
// xg prefetch after publish (shadow overlaps propagation window).
__global__ __launch_bounds__(256, 2) void lstm_persist(
    const u16* __restrict__ w_hh,        // [2][2048][512]
    const u16* __restrict__ xgT,         // [2][2048][16384]  col = t*64+b
    u16* __restrict__ h_all,             // [256*64][1024]
    unsigned* __restrict__ flags)        // [8 groups * 64] counters, 256B apart
{
    __shared__ u16 wlds[4 * 16 * 64 * 8];    // [G][kk][lane][8 bf16] = 64 KB
    const int bx = blockIdx.x;
    const int d = bx >> 5, cg = bx & 31;
    const int lane = threadIdx.x & 63, nf = threadIdx.x >> 6;
    const int lrow = lane & 15, lk = lane >> 4;
    const int b = nf * 16 + lrow;        // this lane's batch column

    // ---- stage A fragments into LDS (once): wave nf fills gate G = nf ----
    {
        const int G = nf;
        const u16* wrow = w_hh + ((size_t)d * G4 + G * HH + cg * 16 + lrow) * HH + lk * 8;
        #pragma unroll
        for (int kk = 0; kk < 16; ++kk)
            *reinterpret_cast<v8s*>(&wlds[((G * 16 + kk) * 64 + lane) * 8]) =
                *reinterpret_cast<const v8s*>(wrow + kk * 32);
    }
    __syncthreads();

    float c[4] = {0.f, 0.f, 0.f, 0.f};
    float xg[4][4];
    unsigned* cnt = flags + (d * 4 + nf) * 64;   // this wave's group counter

    // xg for step 0
    {
        const int t0 = d ? (TT - 1) : 0;
        const u16* xgb = xgT + (size_t)d * G4 * MTB + (size_t)t0 * BB + b;
        #pragma unroll
        for (int G = 0; G < 4; ++G)
            #pragma unroll
            for (int r = 0; r < 4; ++r)
                xg[G][r] = bf2f(xgb[(size_t)(G * HH + cg * 16 + lk * 4 + r) * MTB]);
    }

    for (int s = 0; s < TT; ++s) {
        const int t = d ? (TT - 1 - s) : s;
        v4f acc[4] = {};
        if (s > 0) {
            // ---- prefetch kk=0..3 A-fragments from LDS (overlaps the poll) ----
            v8s af0[4][4];
            #pragma unroll
            for (int G = 0; G < 4; ++G)
                #pragma unroll
                for (int kk = 0; kk < 4; ++kk)
                    af0[G][kk] = *reinterpret_cast<const v8s*>(
                        &wlds[((G * 16 + kk) * 64 + lane) * 8]);
            // ---- wait: group counter reaches 32*s (one merged transaction/poll) ----
            const unsigned tgt = 32u * (unsigned)s;
            while (true) {
                unsigned fv = __hip_atomic_load(cnt, __ATOMIC_RELAXED,
                                                __HIP_MEMORY_SCOPE_AGENT);
                if (__all((int)(fv >= tgt))) break;
            }
            asm volatile("" ::: "memory");       // no load hoisting above the poll
            // ---- load h[tprev] B-fragments (16 x 16B, agent-coherent) ----
            const int tprev = d ? (t + 1) : (t - 1);
            const u16* hp = h_all + ((size_t)tprev * BB + b) * 1024 + d * HH + lk * 8;
            v8s bf_[16];
            #pragma unroll
            for (int kk = 0; kk < 16; ++kk) {
                union { u64 w[2]; v8s v; } u;
                const u16* p = hp + kk * 32;
                u.w[0] = __hip_atomic_load((const u64*)p,
                                           __ATOMIC_RELAXED, __HIP_MEMORY_SCOPE_AGENT);
                u.w[1] = __hip_atomic_load((const u64*)(p + 4),
                                           __ATOMIC_RELAXED, __HIP_MEMORY_SCOPE_AGENT);
                bf_[kk] = u.v;
            }
            // ---- MFMA: prefetched kk<4, then LDS-streamed kk=4..15 ----
            #pragma unroll
            for (int kk = 0; kk < 4; ++kk)
                #pragma unroll
                for (int G = 0; G < 4; ++G)
                    acc[G] = __builtin_amdgcn_mfma_f32_16x16x32_bf16(af0[G][kk], bf_[kk], acc[G], 0, 0, 0);
            #pragma unroll
            for (int kk = 4; kk < 16; ++kk)
                #pragma unroll
                for (int G = 0; G < 4; ++G) {
                    v8s af = *reinterpret_cast<const v8s*>(
                        &wlds[((G * 16 + kk) * 64 + lane) * 8]);
                    acc[G] = __builtin_amdgcn_mfma_f32_16x16x32_bf16(af, bf_[kk], acc[G], 0, 0, 0);
                }
        }
        // ---- gates + state update (all in this lane) ----
        ushort4 hout;
        #pragma unroll
        for (int r = 0; r < 4; ++r) {
            float pi = acc[0][r] + xg[0][r];
            float pf = acc[1][r] + xg[1][r];
            float pg = acc[2][r] + xg[2][r];
            float po = acc[3][r] + xg[3][r];
            float iv = sigm(pi), fv = sigm(pf), gv = tanh_(pg), ov = sigm(po);
            float cc = fv * c[r] + iv * gv;
            c[r] = cc;
            ((u16*)&hout)[r] = f2bf(ov * tanh_(cc));
        }
        // h[t][b][d*512 + cg*16 + lk*4 .. +3]  (8B agent store)
        union { ushort4 v; u64 q; } hu; hu.v = hout;
        __hip_atomic_store((u64*)(
                h_all + ((size_t)t * BB + b) * 1024 + d * HH + cg * 16 + lk * 4),
            hu.q, __ATOMIC_RELAXED, __HIP_MEMORY_SCOPE_AGENT);
        // drain this wave's h store, then publish via near-memory RMW
        asm volatile("s_waitcnt vmcnt(0)" ::: "memory");
        if (lane == 0)
            __hip_atomic_fetch_add(cnt, 1u, __ATOMIC_RELAXED, __HIP_MEMORY_SCOPE_AGENT);
        // ---- prefetch next step's xg (shadow overlaps the propagation window) ----
        if (s + 1 < TT) {
            const int tn = d ? (TT - 2 - s) : (s + 1);
            const u16* xgb = xgT + (size_t)d * G4 * MTB + (size_t)tn * BB + b;
            #pragma unroll
            for (int G = 0; G < 4; ++G)
                #pragma unroll
                for (int r = 0; r < 4; ++r)
                    xg[G][r] = bf2f(xgb[(size_t)(G * HH + cg * 16 + lk * 4 + r) * MTB]);
        }
    }
}

extern "C" void kernel_launch(void* const* d_in, const int* in_sizes, int n_in,
                              void* d_out, int out_size, void* d_ws, size_t ws_size,
                              hipStream_t stream) {
    const float* x    = (const float*)d_in[0];
    const float* wihf = (const float*)d_in[1];
    const float* whhf = (const float*)d_in[2];
    const float* bihf = (const float*)d_in[3];
    const float* bhhf = (const float*)d_in[4];
    const float* wihb = (const float*)d_in[5];
    const float* whhb = (const float*)d_in[6];
    const float* bihb = (const float*)d_in[7];
    const float* bhhb = (const float*)d_in[8];
    const float* fcw  = (const float*)d_in[9];
    const float* fcb  = (const float*)d_in[10];

    char* ws = (char*)d_ws;
    size_t off = 0;
    auto alloc = [&](size_t bytes) {
        off = (off + 255) & ~(size_t)255;
        char* p = ws + off; off += bytes; return p;
    };
    u16* x_bf    = (u16*)alloc((size_t)MTB * 512 * 2);        // 16.8 MB
    u16* wih_bf  = (u16*)alloc((size_t)2 * G4 * 512 * 2);     // 4.2 MB
    u16* whh_bf  = (u16*)alloc((size_t)2 * G4 * 512 * 2);     // 4.2 MB
    u16* fcw_bf  = (u16*)alloc((size_t)512 * 1024 * 2);       // 1.0 MB
    u16* xgT     = (u16*)alloc((size_t)2 * G4 * MTB * 2);     // 134.2 MB
    u16* h_all   = (u16*)alloc((size_t)MTB * 1024 * 2);       // 33.6 MB
    unsigned* flags = (unsigned*)alloc(8 * 64 * sizeof(unsigned));
    (void)ws_size;

    // ---- convert inputs to bf16 ----
    cvt_bf16<<<1024, 256, 0, stream>>>(x, x_bf, MTB * 512);
    cvt_bf16<<<256, 256, 0, stream>>>(wihf, wih_bf, G4 * 512);
    cvt_bf16<<<256, 256, 0, stream>>>(wihb, wih_bf + (size_t)G4 * 512, G4 * 512);
    cvt_bf16<<<256, 256, 0, stream>>>(whhf, whh_bf, G4 * 512);
    cvt_bf16<<<256, 256, 0, stream>>>(whhb, whh_bf + (size_t)G4 * 512, G4 * 512);
    cvt_bf16<<<128, 256, 0, stream>>>(fcw, fcw_bf, 512 * 1024);

    // ---- phase 1: xgT[d] = w_ih[d] @ x^T + (b_ih + b_hh), bf16 out, gate-major ----
    gemm_bt<true, true><<<dim3(MTB / 128, G4 / 128), 256, 0, stream>>>(
        wih_bf, x_bf, xgT, bihf, bhhf, G4, MTB, 512);
    gemm_bt<true, true><<<dim3(MTB / 128, G4 / 128), 256, 0, stream>>>(
        wih_bf + (size_t)G4 * 512, x_bf, xgT + (size_t)G4 * MTB, bihb, bhhb, G4, MTB, 512);

    // ---- phase 2: persistent recurrence, aggregated-counter sync (R11) ----
    hipMemsetAsync(flags, 0, 8 * 64 * sizeof(unsigned), stream);
    lstm_persist<<<64, 256, 0, stream>>>(whh_bf, xgT, h_all, flags);

    // ---- phase 3: out = h_all @ fc_w^T + fc_b, fp32 out ----
    gemm_bt<false, false><<<dim3(512 / 128, MTB / 128), 256, 0, stream>>>(
        h_all, fcw_bf, d_out, fcb, nullptr, MTB, 512, 1024);
}

// Round 19
// 1560.530 us; speedup vs baseline: 1.9489x; 1.0189x over previous
//
#include <hip/hip_runtime.h>

typedef unsigned short u16;
typedef unsigned int u32;
typedef unsigned long long u64;
typedef short v8s __attribute__((ext_vector_type(8)));
typedef float v4f __attribute__((ext_vector_type(4)));

// T=256, B=64, NIN=H=512, NOUT=512, 4H=2048, T*B=16384
#define TT 256
#define BB 64
#define HH 512
#define G4 2048
#define MTB 16384

static __device__ __forceinline__ float bf2f(u16 u) {
    u32 x = ((u32)u) << 16;
    union { u32 i; float f; } c; c.i = x; return c.f;
}
static __device__ __forceinline__ u16 f2bf(float f) {
    union { float f; u32 i; } c; c.f = f;
    u32 u = c.i;
    u += 0x7fffu + ((u >> 16) & 1u);   // RNE
    return (u16)(u >> 16);
}

__global__ __launch_bounds__(256) void cvt_bf16(const float* __restrict__ src,
                                                u16* __restrict__ dst, int n) {
    int i = blockIdx.x * blockDim.x + threadIdx.x;
    int stride = gridDim.x * blockDim.x;
    for (int j = i * 4; j < n; j += stride * 4) {
        float4 v = *reinterpret_cast<const float4*>(src + j);
        ushort4 o;
        o.x = f2bf(v.x); o.y = f2bf(v.y); o.z = f2bf(v.z); o.w = f2bf(v.w);
        *reinterpret_cast<ushort4*>(dst + j) = o;
    }
}

// C[M][N] = A[M][K] * B[N][K]^T (+ bias).  A,B bf16 K-contiguous; 128x128 tile, BK=64,
// 4 waves in 2x2, each wave 64x64 = 4x4 16x16x32 fragments. M,N,K multiples of 128.
// Register-staged LDS fill (R11 configuration — measured best; the gload_lds width-16
// variant regressed ~90us total in R18 at this tile shape).
template<bool OUT_BF16, bool BIAS_M>
__global__ __launch_bounds__(256) void gemm_bt(const u16* __restrict__ A,
                                               const u16* __restrict__ Bm,
                                               void* __restrict__ Cv,
                                               const float* __restrict__ bias1,
                                               const float* __restrict__ bias2,
                                               int M, int N, int K) {
    __shared__ u16 lds_a[128 * 64];
    __shared__ u16 lds_b[128 * 64];
    const int tid = threadIdx.x, lane = tid & 63;
    const int m0 = blockIdx.y * 128, n0 = blockIdx.x * 128;
    const int wid = tid >> 6, wm = wid >> 1, wn = wid & 1;
    v4f acc[4][4] = {};

    const int srow  = tid >> 3;        // 0..31: row within 32-row staging stripe
    const int skoff = (tid & 7) * 8;   // bf16 elements within 64-wide k
    const u16* Ag = A + (size_t)(m0 + srow) * K + skoff;
    const u16* Bg = Bm + (size_t)(n0 + srow) * K + skoff;
    u16* la = lds_a + srow * 64 + skoff;
    u16* lb = lds_b + srow * 64 + skoff;

    for (int k0 = 0; k0 < K; k0 += 64) {
        #pragma unroll
        for (int q = 0; q < 4; ++q) {
            *reinterpret_cast<v8s*>(la + q * 32 * 64) =
                *reinterpret_cast<const v8s*>(Ag + (size_t)q * 32 * K + k0);
            *reinterpret_cast<v8s*>(lb + q * 32 * 64) =
                *reinterpret_cast<const v8s*>(Bg + (size_t)q * 32 * K + k0);
        }
        __syncthreads();
        #pragma unroll
        for (int kk = 0; kk < 2; ++kk) {
            v8s af[4], bfr[4];
            #pragma unroll
            for (int i = 0; i < 4; ++i)
                af[i] = *reinterpret_cast<const v8s*>(
                    lds_a + (wm * 64 + i * 16 + (lane & 15)) * 64 + kk * 32 + (lane >> 4) * 8);
            #pragma unroll
            for (int i = 0; i < 4; ++i)
                bfr[i] = *reinterpret_cast<const v8s*>(
                    lds_b + (wn * 64 + i * 16 + (lane & 15)) * 64 + kk * 32 + (lane >> 4) * 8);
            #pragma unroll
            for (int i = 0; i < 4; ++i)
                #pragma unroll
                for (int j = 0; j < 4; ++j)
                    acc[i][j] = __builtin_amdgcn_mfma_f32_16x16x32_bf16(af[i], bfr[j], acc[i][j], 0, 0, 0);
        }
        __syncthreads();
    }
    // epilogue: D col = lane&15 (n), row = (lane>>4)*4 + reg (m)
    #pragma unroll
    for (int i = 0; i < 4; ++i) {
        #pragma unroll
        for (int j = 0; j < 4; ++j) {
            #pragma unroll
            for (int r = 0; r < 4; ++r) {
                int m = m0 + wm * 64 + i * 16 + (lane >> 4) * 4 + r;
                int n = n0 + wn * 64 + j * 16 + (lane & 15);
                float v = acc[i][j][r];
                if (BIAS_M) { v += bias1[m]; if (bias2) v += bias2[m]; }
                else        { v += bias1[n]; }
                if (OUT_BF16) ((u16*)Cv)[(size_t)m * N + n] = f2bf(v);
                else          ((float*)Cv)[(size_t)m * N + n] = v;
            }
        }
    }
}

static __device__ __forceinline__ float sigm(float x) { return 1.f / (1.f + __expf(-x)); }
static __device__ __forceinline__ float tanh_(float x) { return 2.f / (1.f + __expf(-2.f * x)) - 1.f; }

// Persistent bidirectional LSTM recurrence — R11 verbatim (session-best: 1498 total).
// Structural floor: 256 sequential sync rounds x (~4us agent-scope chain + ~1.3us
// work). The ~4us is invariant to poll traffic (R11), publish mechanism (R9/R11),
// flag granularity (R6/R11), wave packing (R12), phase interleave (R16), direction
// fusion (R9), XCD-local L2 (R13: placement-unsafe, hangs), and fused detect+data
// transport (R7/R14/R15/R17: arrival-skew retry storms). Escapes blocked by physics:
// batch-partitioned single-block sync needs w_hh 2MB/dir > on-CU storage; fewer
// rounds impossible (nonlinear sequential recurrence).
// One aggregated counter per (d,nf) group; producers lane0 fetch_add (near-memory
// RMW); consumers all-lane same-address load (one merged transaction per poll).
// w_hh slice (64KB) LDS-resident as [G][kk][lane]*16B fragments (conflict-free
// ds_read_b128); xg prefetch after publish (shadow overlaps propagation window).
__global__ __launch_bounds__(256, 2) void lstm_persist(
    const u16* __restrict__ w_hh,        // [2][2048][512]
    const u16* __restrict__ xgT,         // [2][2048][16384]  col = t*64+b
    u16* __restrict__ h_all,             // [256*64][1024]
    unsigned* __restrict__ flags)        // [8 groups * 64] counters, 256B apart
{
    __shared__ u16 wlds[4 * 16 * 64 * 8];    // [G][kk][lane][8 bf16] = 64 KB
    const int bx = blockIdx.x;
    const int d = bx >> 5, cg = bx & 31;
    const int lane = threadIdx.x & 63, nf = threadIdx.x >> 6;
    const int lrow = lane & 15, lk = lane >> 4;
    const int b = nf * 16 + lrow;        // this lane's batch column

    // ---- stage A fragments into LDS (once): wave nf fills gate G = nf ----
    {
        const int G = nf;
        const u16* wrow = w_hh + ((size_t)d * G4 + G * HH + cg * 16 + lrow) * HH + lk * 8;
        #pragma unroll
        for (int kk = 0; kk < 16; ++kk)
            *reinterpret_cast<v8s*>(&wlds[((G * 16 + kk) * 64 + lane) * 8]) =
                *reinterpret_cast<const v8s*>(wrow + kk * 32);
    }
    __syncthreads();

    float c[4] = {0.f, 0.f, 0.f, 0.f};
    float xg[4][4];
    unsigned* cnt = flags + (d * 4 + nf) * 64;   // this wave's group counter

    // xg for step 0
    {
        const int t0 = d ? (TT - 1) : 0;
        const u16* xgb = xgT + (size_t)d * G4 * MTB + (size_t)t0 * BB + b;
        #pragma unroll
        for (int G = 0; G < 4; ++G)
            #pragma unroll
            for (int r = 0; r < 4; ++r)
                xg[G][r] = bf2f(xgb[(size_t)(G * HH + cg * 16 + lk * 4 + r) * MTB]);
    }

    for (int s = 0; s < TT; ++s) {
        const int t = d ? (TT - 1 - s) : s;
        v4f acc[4] = {};
        if (s > 0) {
            // ---- prefetch kk=0..3 A-fragments from LDS (overlaps the poll) ----
            v8s af0[4][4];
            #pragma unroll
            for (int G = 0; G < 4; ++G)
                #pragma unroll
                for (int kk = 0; kk < 4; ++kk)
                    af0[G][kk] = *reinterpret_cast<const v8s*>(
                        &wlds[((G * 16 + kk) * 64 + lane) * 8]);
            // ---- wait: group counter reaches 32*s (one merged transaction/poll) ----
            const unsigned tgt = 32u * (unsigned)s;
            while (true) {
                unsigned fv = __hip_atomic_load(cnt, __ATOMIC_RELAXED,
                                                __HIP_MEMORY_SCOPE_AGENT);
                if (__all((int)(fv >= tgt))) break;
            }
            asm volatile("" ::: "memory");       // no load hoisting above the poll
            // ---- load h[tprev] B-fragments (16 x 16B, agent-coherent) ----
            const int tprev = d ? (t + 1) : (t - 1);
            const u16* hp = h_all + ((size_t)tprev * BB + b) * 1024 + d * HH + lk * 8;
            v8s bf_[16];
            #pragma unroll
            for (int kk = 0; kk < 16; ++kk) {
                union { u64 w[2]; v8s v; } u;
                const u16* p = hp + kk * 32;
                u.w[0] = __hip_atomic_load((const u64*)p,
                                           __ATOMIC_RELAXED, __HIP_MEMORY_SCOPE_AGENT);
                u.w[1] = __hip_atomic_load((const u64*)(p + 4),
                                           __ATOMIC_RELAXED, __HIP_MEMORY_SCOPE_AGENT);
                bf_[kk] = u.v;
            }
            // ---- MFMA: prefetched kk<4, then LDS-streamed kk=4..15 ----
            #pragma unroll
            for (int kk = 0; kk < 4; ++kk)
                #pragma unroll
                for (int G = 0; G < 4; ++G)
                    acc[G] = __builtin_amdgcn_mfma_f32_16x16x32_bf16(af0[G][kk], bf_[kk], acc[G], 0, 0, 0);
            #pragma unroll
            for (int kk = 4; kk < 16; ++kk)
                #pragma unroll
                for (int G = 0; G < 4; ++G) {
                    v8s af = *reinterpret_cast<const v8s*>(
                        &wlds[((G * 16 + kk) * 64 + lane) * 8]);
                    acc[G] = __builtin_amdgcn_mfma_f32_16x16x32_bf16(af, bf_[kk], acc[G], 0, 0, 0);
                }
        }
        // ---- gates + state update (all in this lane) ----
        ushort4 hout;
        #pragma unroll
        for (int r = 0; r < 4; ++r) {
            float pi = acc[0][r] + xg[0][r];
            float pf = acc[1][r] + xg[1][r];
            float pg = acc[2][r] + xg[2][r];
            float po = acc[3][r] + xg[3][r];
            float iv = sigm(pi), fv = sigm(pf), gv = tanh_(pg), ov = sigm(po);
            float cc = fv * c[r] + iv * gv;
            c[r] = cc;
            ((u16*)&hout)[r] = f2bf(ov * tanh_(cc));
        }
        // h[t][b][d*512 + cg*16 + lk*4 .. +3]  (8B agent store)
        union { ushort4 v; u64 q; } hu; hu.v = hout;
        __hip_atomic_store((u64*)(
                h_all + ((size_t)t * BB + b) * 1024 + d * HH + cg * 16 + lk * 4),
            hu.q, __ATOMIC_RELAXED, __HIP_MEMORY_SCOPE_AGENT);
        // drain this wave's h store, then publish via near-memory RMW
        asm volatile("s_waitcnt vmcnt(0)" ::: "memory");
        if (lane == 0)
            __hip_atomic_fetch_add(cnt, 1u, __ATOMIC_RELAXED, __HIP_MEMORY_SCOPE_AGENT);
        // ---- prefetch next step's xg (shadow overlaps the propagation window) ----
        if (s + 1 < TT) {
            const int tn = d ? (TT - 2 - s) : (s + 1);
            const u16* xgb = xgT + (size_t)d * G4 * MTB + (size_t)tn * BB + b;
            #pragma unroll
            for (int G = 0; G < 4; ++G)
                #pragma unroll
                for (int r = 0; r < 4; ++r)
                    xg[G][r] = bf2f(xgb[(size_t)(G * HH + cg * 16 + lk * 4 + r) * MTB]);
        }
    }
}

extern "C" void kernel_launch(void* const* d_in, const int* in_sizes, int n_in,
                              void* d_out, int out_size, void* d_ws, size_t ws_size,
                              hipStream_t stream) {
    const float* x    = (const float*)d_in[0];
    const float* wihf = (const float*)d_in[1];
    const float* whhf = (const float*)d_in[2];
    const float* bihf = (const float*)d_in[3];
    const float* bhhf = (const float*)d_in[4];
    const float* wihb = (const float*)d_in[5];
    const float* whhb = (const float*)d_in[6];
    const float* bihb = (const float*)d_in[7];
    const float* bhhb = (const float*)d_in[8];
    const float* fcw  = (const float*)d_in[9];
    const float* fcb  = (const float*)d_in[10];

    char* ws = (char*)d_ws;
    size_t off = 0;
    auto alloc = [&](size_t bytes) {
        off = (off + 255) & ~(size_t)255;
        char* p = ws + off; off += bytes; return p;
    };
    u16* x_bf    = (u16*)alloc((size_t)MTB * 512 * 2);        // 16.8 MB
    u16* wih_bf  = (u16*)alloc((size_t)2 * G4 * 512 * 2);     // 4.2 MB
    u16* whh_bf  = (u16*)alloc((size_t)2 * G4 * 512 * 2);     // 4.2 MB
    u16* fcw_bf  = (u16*)alloc((size_t)512 * 1024 * 2);       // 1.0 MB
    u16* xgT     = (u16*)alloc((size_t)2 * G4 * MTB * 2);     // 134.2 MB
    u16* h_all   = (u16*)alloc((size_t)MTB * 1024 * 2);       // 33.6 MB
    unsigned* flags = (unsigned*)alloc(8 * 64 * sizeof(unsigned));
    (void)ws_size;

    // ---- convert inputs to bf16 ----
    cvt_bf16<<<1024, 256, 0, stream>>>(x, x_bf, MTB * 512);
    cvt_bf16<<<256, 256, 0, stream>>>(wihf, wih_bf, G4 * 512);
    cvt_bf16<<<256, 256, 0, stream>>>(wihb, wih_bf + (size_t)G4 * 512, G4 * 512);
    cvt_bf16<<<256, 256, 0, stream>>>(whhf, whh_bf, G4 * 512);
    cvt_bf16<<<256, 256, 0, stream>>>(whhb, whh_bf + (size_t)G4 * 512, G4 * 512);
    cvt_bf16<<<128, 256, 0, stream>>>(fcw, fcw_bf, 512 * 1024);

    // ---- phase 1: xgT[d] = w_ih[d] @ x^T + (b_ih + b_hh), bf16 out, gate-major ----
    gemm_bt<true, true><<<dim3(MTB / 128, G4 / 128), 256, 0, stream>>>(
        wih_bf, x_bf, xgT, bihf, bhhf, G4, MTB, 512);
    gemm_bt<true, true><<<dim3(MTB / 128, G4 / 128), 256, 0, stream>>>(
        wih_bf + (size_t)G4 * 512, x_bf, xgT + (size_t)G4 * MTB, bihb, bhhb, G4, MTB, 512);

    // ---- phase 2: persistent recurrence, aggregated-counter sync (R11) ----
    hipMemsetAsync(flags, 0, 8 * 64 * sizeof(unsigned), stream);
    lstm_persist<<<64, 256, 0, stream>>>(whh_bf, xgT, h_all, flags);

    // ---- phase 3: out = h_all @ fc_w^T + fc_b, fp32 out ----
    gemm_bt<false, false><<<dim3(512 / 128, MTB / 128), 256, 0, stream>>>(
        h_all, fcw_bf, d_out, fcb, nullptr, MTB, 512, 1024);
}